// Round 13
// baseline (133.965 us; speedup 1.0000x reference)
//
#include <hip/hip_runtime.h>
#include <hip/hip_bf16.h>
#include <stdint.h>

// ---------------- problem constants ----------------
#define PDIM   1024
#define HEADS  16
#define DHEAD  64
#define BATCH  2
#define SEQ    2048
#define ROWS   (BATCH*SEQ)     // 4096
#define NBH    (BATCH*HEADS)   // 32

typedef __attribute__((ext_vector_type(8))) short s8v;     // 8 x bf16 (4 VGPR)
typedef __attribute__((ext_vector_type(4))) float f32x4;   // 16x16 MFMA accum
typedef __attribute__((ext_vector_type(16))) float f32x16; // 32x32 MFMA accum
typedef unsigned short ushort_t;
typedef unsigned int   uint32;

// Q pre-scale: DIM_HEAD^-0.5 * log2(e)  (folded into Wqt prep, Q columns)
#define QSCALE 0.18033688011112042f
// fixed softmax bias (log2 units): p = exp2(s - MFIX); cancels in num/denom
#define MFIX 12.0f

// ---------------- helpers ----------------
__device__ __forceinline__ ushort_t f2bf(float x){
  union { float f; uint32 u; } v; v.f = x;
  uint32 r = v.u + 0x7FFFu + ((v.u >> 16) & 1u);   // RTN-even
  return (ushort_t)(r >> 16);
}
__device__ __forceinline__ uint32 cvt_pk_bf16(float lo, float hi){
  uint32 r;
  asm("v_cvt_pk_bf16_f32 %0, %1, %2" : "=v"(r) : "v"(lo), "v"(hi));
  return r;   // bf16(lo) in [15:0], bf16(hi) in [31:16]
}

typedef const __attribute__((address_space(1))) void* gas_ptr;
typedef __attribute__((address_space(3))) void*       las_ptr;
__device__ __forceinline__ void g2l16(const void* g, void* l){
  // dest = wave-uniform LDS base; HW adds lane*16
  __builtin_amdgcn_global_load_lds((gas_ptr)g, (las_ptr)l, 16, 0, 0);
}

// ---------------- fused prep: x cvt + w_qkv tcvt (Q-cols pre-scaled) + w_out tcvt ----------------
__global__ __launch_bounds__(256) void k_prep(
    const float* __restrict__ x, const float* __restrict__ w_qkv,
    const float* __restrict__ w_out,
    ushort_t* __restrict__ Xh, ushort_t* __restrict__ Wqt_h,
    ushort_t* __restrict__ Wot_h){
  __shared__ float tile[64][65];
  const int bid = blockIdx.x;
  if (bid < 4096){
    int i = bid * 256 + threadIdx.x;
    float4 v = reinterpret_cast<const float4*>(x)[i];
    reinterpret_cast<ushort4*>(Xh)[i] =
        make_ushort4(f2bf(v.x), f2bf(v.y), f2bf(v.z), f2bf(v.w));
    return;
  }
  const float* src; ushort_t* dst; int R, C, cb, rb;
  float scl = 1.f;
  if (bid < 4864){
    int t = bid - 4096; src = w_qkv; dst = Wqt_h; R = 1024; C = 3072;
    cb = (t % 48) * 64; rb = (t / 48) * 64;
    if (cb < 1024) scl = QSCALE;          // Q columns: fold DIM_HEAD^-0.5*log2(e)
  } else {
    int t = bid - 4864; src = w_out; dst = Wot_h; R = 1024; C = 1024;
    cb = (t % 16) * 64; rb = (t / 16) * 64;
  }
  int t = threadIdx.x;
  int lw = t >> 6, lc = t & 63;
#pragma unroll
  for (int i = 0; i < 16; i++){
    int r = i * 4 + lw;
    tile[r][lc] = src[(size_t)(rb + r) * C + cb + lc];
  }
  __syncthreads();
#pragma unroll
  for (int i = 0; i < 16; i++){
    int c = i * 4 + lw;
    dst[(size_t)(cb + c) * R + rb + lc] = f2bf(tile[lc][c] * scl);
  }
}

// ---------------- GEMM core (128x128 tile, BK=64, 4 waves, dbuf + swizzle) ----------------
#define GBM 128
#define GBN 128
#define GBK 64

// ---------------- QKV projection GEMM, fused per-head epilogue ----------------
__global__ __launch_bounds__(256, 2) void k_gemm_qkv(
    const ushort_t* __restrict__ Xh, const ushort_t* __restrict__ Wqt_h,
    ushort_t* __restrict__ Qh, ushort_t* __restrict__ Kh, ushort_t* __restrict__ Vth){
  __shared__ __align__(16) ushort_t Asm[2][GBM * GBK];
  __shared__ __align__(16) ushort_t Bsm[2][GBM * GBK];
  const int tid  = threadIdx.x;
  const int wave = tid >> 6, lane = tid & 63;
  const int mb = blockIdx.y * GBM, nb = blockIdx.x * GBN;
  const int wr = wave >> 1, wc = wave & 1;
  const int l15 = lane & 15, l4 = lane >> 4;
  const int rsub = lane >> 3;
  const int schunk = ((lane & 7) ^ rsub) * 8;  // source-swizzled chunk
  f32x4 acc[4][4] = {};

  auto stage = [&](int buf, int kb){
    int k0 = kb * GBK;
#pragma unroll
    for (int i = 0; i < 4; i++){
      int row = (i * 4 + wave) * 8 + rsub;
      g2l16(Xh    + (size_t)(mb + row) * 1024 + k0 + schunk, &Asm[buf][(i * 4 + wave) * 512]);
      g2l16(Wqt_h + (size_t)(nb + row) * 1024 + k0 + schunk, &Bsm[buf][(i * 4 + wave) * 512]);
    }
  };

  stage(0, 0);

  for (int kb = 0; kb < 16; kb++){
    const int cur = kb & 1;
    if (kb < 15){
      stage(cur ^ 1, kb + 1);
      asm volatile("s_waitcnt vmcnt(8)" ::: "memory");
    } else {
      asm volatile("s_waitcnt vmcnt(0)" ::: "memory");
    }
    __builtin_amdgcn_s_barrier();
    __builtin_amdgcn_s_setprio(1);
#pragma unroll
    for (int ks = 0; ks < 2; ks++){
      s8v af[4], bfr[4];
#pragma unroll
      for (int f = 0; f < 4; f++){
        int ch = (((ks * 4 + l4) ^ (l15 & 7)) << 3);
        af[f]  = *reinterpret_cast<const s8v*>(&Asm[cur][(wr * 64 + f * 16 + l15) * 64 + ch]);
        bfr[f] = *reinterpret_cast<const s8v*>(&Bsm[cur][(wc * 64 + f * 16 + l15) * 64 + ch]);
      }
#pragma unroll
      for (int fr = 0; fr < 4; fr++)
#pragma unroll
        for (int fc = 0; fc < 4; fc++)
          acc[fr][fc] = __builtin_amdgcn_mfma_f32_16x16x32_bf16(af[fr], bfr[fc], acc[fr][fc], 0, 0, 0);
    }
    __builtin_amdgcn_s_setprio(0);
    __builtin_amdgcn_s_barrier();
  }

  // fused epilogue: cols [nb,nb+128) all in one part (1024 % 128 == 0)
  const int pnum = nb >> 10;
#pragma unroll
  for (int fr = 0; fr < 4; fr++){
    int row  = mb + wr * 64 + fr * 16 + l4 * 4;
    int b    = row >> 11;
    int nseq = row & 2047;
#pragma unroll
    for (int fc = 0; fc < 4; fc++){
      int col = nb + wc * 64 + fc * 16 + l15;
      int rem = col & 1023;
      int h = rem >> 6, d = rem & 63;
      int bh = b * 16 + h;
      if (pnum == 0){          // Q (scale pre-folded into W)
        size_t base = ((size_t)bh * SEQ + nseq) * 64 + d;
#pragma unroll
        for (int r = 0; r < 4; r++)
          Qh[base + (size_t)r * 64] = f2bf(acc[fr][fc][r]);
      } else if (pnum == 1){   // K
        size_t base = ((size_t)bh * SEQ + nseq) * 64 + d;
#pragma unroll
        for (int r = 0; r < 4; r++)
          Kh[base + (size_t)r * 64] = f2bf(acc[fr][fc][r]);
      } else {                 // V: transposed [bh][d][SEQ]
        size_t base = ((size_t)bh * 64 + d) * SEQ + nseq;
        *reinterpret_cast<ushort4*>(&Vth[base]) =
            make_ushort4(f2bf(acc[fr][fc][0]), f2bf(acc[fr][fc][1]),
                         f2bf(acc[fr][fc][2]), f2bf(acc[fr][fc][3]));
      }
    }
  }
}

// ---------------- out-projection GEMM (plain bf16, dbuf + swizzle) ----------------
__global__ __launch_bounds__(256, 2) void k_gemm_out(
    const ushort_t* __restrict__ Ah, const ushort_t* __restrict__ Bth,
    float* __restrict__ C, const float* __restrict__ bias){
  __shared__ __align__(16) ushort_t Asm[2][GBM * GBK];
  __shared__ __align__(16) ushort_t Bsm[2][GBM * GBK];
  const int tid  = threadIdx.x;
  const int wave = tid >> 6, lane = tid & 63;
  const int mb = blockIdx.y * GBM, nb = blockIdx.x * GBN;
  const int wr = wave >> 1, wc = wave & 1;
  const int l15 = lane & 15, l4 = lane >> 4;
  const int rsub = lane >> 3;
  const int schunk = ((lane & 7) ^ rsub) * 8;
  f32x4 acc[4][4] = {};

  auto stage = [&](int buf, int kb){
    int k0 = kb * GBK;
#pragma unroll
    for (int i = 0; i < 4; i++){
      int row = (i * 4 + wave) * 8 + rsub;
      g2l16(Ah  + (size_t)(mb + row) * 1024 + k0 + schunk, &Asm[buf][(i * 4 + wave) * 512]);
      g2l16(Bth + (size_t)(nb + row) * 1024 + k0 + schunk, &Bsm[buf][(i * 4 + wave) * 512]);
    }
  };

  stage(0, 0);

  for (int kb = 0; kb < 16; kb++){
    const int cur = kb & 1;
    if (kb < 15){
      stage(cur ^ 1, kb + 1);
      asm volatile("s_waitcnt vmcnt(8)" ::: "memory");
    } else {
      asm volatile("s_waitcnt vmcnt(0)" ::: "memory");
    }
    __builtin_amdgcn_s_barrier();
    __builtin_amdgcn_s_setprio(1);
#pragma unroll
    for (int ks = 0; ks < 2; ks++){
      s8v af[4], bfr[4];
#pragma unroll
      for (int f = 0; f < 4; f++){
        int ch = (((ks * 4 + l4) ^ (l15 & 7)) << 3);
        af[f]  = *reinterpret_cast<const s8v*>(&Asm[cur][(wr * 64 + f * 16 + l15) * 64 + ch]);
        bfr[f] = *reinterpret_cast<const s8v*>(&Bsm[cur][(wc * 64 + f * 16 + l15) * 64 + ch]);
      }
#pragma unroll
      for (int fr = 0; fr < 4; fr++)
#pragma unroll
        for (int fc = 0; fc < 4; fc++)
          acc[fr][fc] = __builtin_amdgcn_mfma_f32_16x16x32_bf16(af[fr], bfr[fc], acc[fr][fc], 0, 0, 0);
    }
    __builtin_amdgcn_s_setprio(0);
    __builtin_amdgcn_s_barrier();
  }
#pragma unroll
  for (int fr = 0; fr < 4; fr++){
    int row = mb + wr * 64 + fr * 16 + l4 * 4;
#pragma unroll
    for (int fc = 0; fc < 4; fc++){
      int col = nb + wc * 64 + fc * 16 + l15;
      float bv = bias[col];
#pragma unroll
      for (int r = 0; r < 4; r++)
        C[(size_t)(row + r) * 1024 + col] = acc[fr][fc][r] + bv;
    }
  }
}

// ---------------- flash attention (2-wave blocks, KV=32, 4 waves/SIMD) ----------------
// Grid 1024 x 128 threads = 8 blocks/CU (LDS 16KB: K dbuf 8K + V dbuf 8K) ->
// 16 waves/CU = 4/SIMD from independent blocks: hides the per-iter serial chain
// (QK chain -> exp2 -> permlane -> PV chain) that capped r10-r12 at ~50us.
// Same verified 32x32-swapped-QK + in-register-P math as r12, KV tile 32:
// per iter 4 QK mfma + 16 exp2 + 8 cvt_pk + 4 permlane + 4 PV mfma.
// Staging via bumped pointers (+2048/+32 elems per iter) - no per-iter addr VALU.
__global__ __launch_bounds__(128, 4) void k_flash(
    const ushort_t* __restrict__ Qh, const ushort_t* __restrict__ Kh,
    const ushort_t* __restrict__ Vth, ushort_t* __restrict__ Ah){
  __shared__ __align__(16) ushort_t KhS[2][32 * 64];   // [kv][d]
  __shared__ __align__(16) ushort_t VhS[2][64 * 32];   // [d][kv]
  const int lid = blockIdx.x;             // 0..1023
  const int xcd = lid & 7, g = lid >> 3;  // 8 XCDs x 128 blocks
  const int bh = xcd * 4 + (g & 3);       // each XCD owns 4 heads (K/V L2-resident)
  const int qb = (g >> 2) * 64;           // 32 q-tiles of 64
  const int tid = threadIdx.x, wave = tid >> 6, lane = tid & 63;
  const int l31 = lane & 31, hh = lane >> 5;
  const int b = bh >> 4, hd = bh & 15;
  const size_t hbase = (size_t)bh * SEQ * 64;
  const int rsub = lane >> 3;                            // 0..7
  const int schunkK = ((lane & 7) ^ rsub) * 8;           // K stage swizzle (8 chunks)
  const int schunkV = ((lane & 3) ^ ((lane >> 2) & 3)) * 8;  // V stage swizzle (4 chunks)

  // frag-read element offsets
  int fchK[4], fchV[2];
#pragma unroll
  for (int s = 0; s < 4; s++) fchK[s] = (((2 * s + hh) ^ (l31 & 7)) << 3);
#pragma unroll
  for (int s = 0; s < 2; s++) fchV[s] = (((2 * s + hh) ^ (l31 & 3)) << 3);
  const int fbK = l31 * 64;
  const int fbV = l31 * 32;

  // Q as B-operand frags: lane(q=l31, hh) holds Q[q][d = 16s + 8hh + 0..7]
  s8v qf[4];
#pragma unroll
  for (int s = 0; s < 4; s++)
    qf[s] = *reinterpret_cast<const s8v*>(
        &Qh[hbase + (size_t)(qb + wave * 32 + l31) * 64 + s * 16 + hh * 8]);

  f32x16 o0 = {}, o1 = {};   // O[q][d 0..31], O[q][d 32..63]
  float lsum = 0.f;

  // bumped staging pointers (kt=0 bases)
  const ushort_t* kp0 = Kh + hbase + (size_t)(wave * 8 + rsub) * 64 + schunkK;
  const ushort_t* kp1 = kp0 + (size_t)16 * 64;
  const ushort_t* vp0 = Vth + ((size_t)bh * 64 + wave * 16 + (lane >> 2)) * SEQ + schunkV;
  const ushort_t* vp1 = vp0 + (size_t)32 * SEQ;

  auto stage = [&](int buf){
    g2l16(kp0, &KhS[buf][wave * 512]);        kp0 += 2048;
    g2l16(kp1, &KhS[buf][1024 + wave * 512]); kp1 += 2048;
    g2l16(vp0, &VhS[buf][wave * 512]);        vp0 += 32;
    g2l16(vp1, &VhS[buf][1024 + wave * 512]); vp1 += 32;
  };

  stage(0);

  for (int kt = 0; kt < 64; kt++){
    const int cur = kt & 1;
    if (kt < 63){
      stage(cur ^ 1);                                  // next tile's 4 loads in flight
      asm volatile("s_waitcnt vmcnt(4)" ::: "memory"); // current tile's 4 landed
    } else {
      asm volatile("s_waitcnt vmcnt(0)" ::: "memory");
    }
    __builtin_amdgcn_s_barrier();

    // QK: C[kv 0..31][q], K-dim = 64 d in 4 steps
    f32x16 s0 = {};
    __builtin_amdgcn_s_setprio(1);
#pragma unroll
    for (int s = 0; s < 4; s++){
      s8v kf = *reinterpret_cast<const s8v*>(&KhS[cur][fbK + fchK[s]]);
      s0 = __builtin_amdgcn_mfma_f32_32x32x16_bf16(kf, qf[s], s0, 0, 0, 0);
    }
    __builtin_amdgcn_s_setprio(0);

    // fixed-max softmax + pack
    uint32 w[8];
#pragma unroll
    for (int t = 0; t < 8; t++){
      float pa = __builtin_amdgcn_exp2f(s0[2 * t]     - MFIX);
      float pb = __builtin_amdgcn_exp2f(s0[2 * t + 1] - MFIX);
      lsum += pa + pb;
      w[t] = cvt_pk_bf16(pa, pb);
    }

    // PV: O[q][d] += P[32q x 32kv] . V[32kv x 64d]; P frags via permlane swaps
    __builtin_amdgcn_s_setprio(1);
#pragma unroll
    for (int s = 0; s < 2; s++){
      const int u = 4 * s;
      uint32 m0 = w[u],     m2 = w[u + 2];
      uint32 m1 = w[u + 1], m3 = w[u + 3];
      asm("v_permlane32_swap_b32 %0, %1" : "+v"(m0), "+v"(m2));
      asm("v_permlane32_swap_b32 %0, %1" : "+v"(m1), "+v"(m3));
      union { uint32 u4[4]; s8v v; } pf;
      pf.u4[0] = m0; pf.u4[1] = m1; pf.u4[2] = m2; pf.u4[3] = m3;
      s8v vf0 = *reinterpret_cast<const s8v*>(&VhS[cur][fbV + fchV[s]]);
      s8v vf1 = *reinterpret_cast<const s8v*>(&VhS[cur][fbV + 1024 + fchV[s]]);
      o0 = __builtin_amdgcn_mfma_f32_32x32x16_bf16(pf.v, vf0, o0, 0, 0, 0);
      o1 = __builtin_amdgcn_mfma_f32_32x32x16_bf16(pf.v, vf1, o1, 0, 0, 0);
    }
    __builtin_amdgcn_s_setprio(0);
    __builtin_amdgcn_s_barrier();   // both waves done reading cur buffers
  }

  // epilogue: lane holds lsum-half for q=l31; combine halves, per-reg shfl
  lsum += __shfl_xor(lsum, 32);
  float linv = 1.f / lsum;
#pragma unroll
  for (int r = 0; r < 16; r++){
    int q = (r & 3) + 8 * (r >> 2) + 4 * hh;
    float sc = __shfl(linv, q);
    int n = qb + wave * 32 + q;
    size_t rowb = (size_t)(b * SEQ + n) * 1024 + hd * 64;
    Ah[rowb + l31]      = f2bf(o0[r] * sc);
    Ah[rowb + 32 + l31] = f2bf(o1[r] * sc);
  }
}

// ---------------- host launch ----------------
extern "C" void kernel_launch(void* const* d_in, const int* in_sizes, int n_in,
                              void* d_out, int out_size, void* d_ws, size_t ws_size,
                              hipStream_t stream){
  const float* x     = (const float*)d_in[0];
  const float* w_qkv = (const float*)d_in[1];
  const float* w_out = (const float*)d_in[2];
  const float* b_out = (const float*)d_in[3];
  float* out = (float*)d_out;
  char* ws = (char*)d_ws;

  ushort_t* Xh    = (ushort_t*)(ws);                      //  8 MB
  ushort_t* Wqt_h = (ushort_t*)(ws + 8388608);            //  6 MB
  ushort_t* Wot_h = (ushort_t*)(ws + 14680064);           //  2 MB
  ushort_t* Qh    = (ushort_t*)(ws + 16777216);           //  8 MB
  ushort_t* Kh    = (ushort_t*)(ws + 25165824);           //  8 MB
  ushort_t* Vth   = (ushort_t*)(ws + 33554432);           //  8 MB
  ushort_t* Ah    = (ushort_t*)(ws + 41943040);           //  8 MB

  // 1. fused prep: x -> Xh; w_qkv -> Wqt_h (T, Q cols pre-scaled); w_out -> Wot_h (T)
  k_prep<<<5120, 256, 0, stream>>>(x, w_qkv, w_out, Xh, Wqt_h, Wot_h);
  // 2. QKV projection with fused per-head epilogue
  k_gemm_qkv<<<dim3(24, 32), 256, 0, stream>>>(Xh, Wqt_h, Qh, Kh, Vth);
  // 3. attention -> Ah (bf16)
  k_flash<<<1024, 128, 0, stream>>>(Qh, Kh, Vth, Ah);
  // 4. out = Ah @ Wot + b_out
  k_gemm_out<<<dim3(8, 32), 256, 0, stream>>>(Ah, Wot_h, out, b_out);
}

// Round 14
// 121.991 us; speedup vs baseline: 1.0982x; 1.0982x over previous
//
#include <hip/hip_runtime.h>
#include <hip/hip_bf16.h>
#include <stdint.h>

// ---------------- problem constants ----------------
#define PDIM   1024
#define HEADS  16
#define DHEAD  64
#define BATCH  2
#define SEQ    2048
#define ROWS   (BATCH*SEQ)     // 4096
#define NBH    (BATCH*HEADS)   // 32

typedef __attribute__((ext_vector_type(8))) short s8v;     // 8 x bf16 (4 VGPR)
typedef __attribute__((ext_vector_type(4))) float f32x4;   // 16x16 MFMA accum
typedef __attribute__((ext_vector_type(16))) float f32x16; // 32x32 MFMA accum
typedef unsigned short ushort_t;
typedef unsigned int   uint32;

// Q pre-scale: DIM_HEAD^-0.5 * log2(e)  (folded into Wqt prep, Q columns)
#define QSCALE 0.18033688011112042f
// fixed softmax bias (log2 units): p = exp2(s - MFIX); cancels in num/denom
#define MFIX 12.0f

// ---------------- helpers ----------------
__device__ __forceinline__ ushort_t f2bf(float x){
  union { float f; uint32 u; } v; v.f = x;
  uint32 r = v.u + 0x7FFFu + ((v.u >> 16) & 1u);   // RTN-even
  return (ushort_t)(r >> 16);
}
__device__ __forceinline__ uint32 cvt_pk_bf16(float lo, float hi){
  uint32 r;
  asm("v_cvt_pk_bf16_f32 %0, %1, %2" : "=v"(r) : "v"(lo), "v"(hi));
  return r;   // bf16(lo) in [15:0], bf16(hi) in [31:16]
}

typedef const __attribute__((address_space(1))) void* gas_ptr;
typedef __attribute__((address_space(3))) void*       las_ptr;
__device__ __forceinline__ void g2l16(const void* g, void* l){
  // dest = wave-uniform LDS base; HW adds lane*16
  __builtin_amdgcn_global_load_lds((gas_ptr)g, (las_ptr)l, 16, 0, 0);
}

// ---------------- fused prep: x cvt + w_qkv tcvt (Q-cols pre-scaled) + w_out tcvt ----------------
__global__ __launch_bounds__(256) void k_prep(
    const float* __restrict__ x, const float* __restrict__ w_qkv,
    const float* __restrict__ w_out,
    ushort_t* __restrict__ Xh, ushort_t* __restrict__ Wqt_h,
    ushort_t* __restrict__ Wot_h){
  __shared__ float tile[64][65];
  const int bid = blockIdx.x;
  if (bid < 4096){
    int i = bid * 256 + threadIdx.x;
    float4 v = reinterpret_cast<const float4*>(x)[i];
    reinterpret_cast<ushort4*>(Xh)[i] =
        make_ushort4(f2bf(v.x), f2bf(v.y), f2bf(v.z), f2bf(v.w));
    return;
  }
  const float* src; ushort_t* dst; int R, C, cb, rb;
  float scl = 1.f;
  if (bid < 4864){
    int t = bid - 4096; src = w_qkv; dst = Wqt_h; R = 1024; C = 3072;
    cb = (t % 48) * 64; rb = (t / 48) * 64;
    if (cb < 1024) scl = QSCALE;          // Q columns: fold DIM_HEAD^-0.5*log2(e)
  } else {
    int t = bid - 4864; src = w_out; dst = Wot_h; R = 1024; C = 1024;
    cb = (t % 16) * 64; rb = (t / 16) * 64;
  }
  int t = threadIdx.x;
  int lw = t >> 6, lc = t & 63;
#pragma unroll
  for (int i = 0; i < 16; i++){
    int r = i * 4 + lw;
    tile[r][lc] = src[(size_t)(rb + r) * C + cb + lc];
  }
  __syncthreads();
#pragma unroll
  for (int i = 0; i < 16; i++){
    int c = i * 4 + lw;
    dst[(size_t)(cb + c) * R + rb + lc] = f2bf(tile[lc][c] * scl);
  }
}

// ---------------- GEMM core (128x128 tile, BK=64, 4 waves, dbuf + swizzle) ----------------
#define GBM 128
#define GBN 128
#define GBK 64

// ---------------- QKV projection GEMM, fused per-head epilogue ----------------
// Epilogue writes: Qh [bh][n][64]; K and V in PRE-FRAGMENTED MFMA-operand order:
//   Kf[((bh*64 + kvtile)*4 + s)*512 + lane*8 + j]   lane=32*hh+l31:
//       K[kvtile*32 + l31][16s + 8hh + j]           (A-operand, 32x32x16)
//   Vf[((bh*64 + kvtile)*4 + step*2 + dhalf)*512 + lane*8 + j]:
//       V[kvtile*32 + 16*step + 8hh + j][32*dhalf + l31]   (B-operand)
__global__ __launch_bounds__(256, 2) void k_gemm_qkv(
    const ushort_t* __restrict__ Xh, const ushort_t* __restrict__ Wqt_h,
    ushort_t* __restrict__ Qh, ushort_t* __restrict__ Kf, ushort_t* __restrict__ Vf){
  __shared__ __align__(16) ushort_t Asm[2][GBM * GBK];
  __shared__ __align__(16) ushort_t Bsm[2][GBM * GBK];
  const int tid  = threadIdx.x;
  const int wave = tid >> 6, lane = tid & 63;
  const int mb = blockIdx.y * GBM, nb = blockIdx.x * GBN;
  const int wr = wave >> 1, wc = wave & 1;
  const int l15 = lane & 15, l4 = lane >> 4;
  const int rsub = lane >> 3;
  const int schunk = ((lane & 7) ^ rsub) * 8;  // source-swizzled chunk
  f32x4 acc[4][4] = {};

  auto stage = [&](int buf, int kb){
    int k0 = kb * GBK;
#pragma unroll
    for (int i = 0; i < 4; i++){
      int row = (i * 4 + wave) * 8 + rsub;
      g2l16(Xh    + (size_t)(mb + row) * 1024 + k0 + schunk, &Asm[buf][(i * 4 + wave) * 512]);
      g2l16(Wqt_h + (size_t)(nb + row) * 1024 + k0 + schunk, &Bsm[buf][(i * 4 + wave) * 512]);
    }
  };

  stage(0, 0);

  for (int kb = 0; kb < 16; kb++){
    const int cur = kb & 1;
    if (kb < 15){
      stage(cur ^ 1, kb + 1);
      asm volatile("s_waitcnt vmcnt(8)" ::: "memory");
    } else {
      asm volatile("s_waitcnt vmcnt(0)" ::: "memory");
    }
    __builtin_amdgcn_s_barrier();
    __builtin_amdgcn_s_setprio(1);
#pragma unroll
    for (int ks = 0; ks < 2; ks++){
      s8v af[4], bfr[4];
#pragma unroll
      for (int f = 0; f < 4; f++){
        int ch = (((ks * 4 + l4) ^ (l15 & 7)) << 3);
        af[f]  = *reinterpret_cast<const s8v*>(&Asm[cur][(wr * 64 + f * 16 + l15) * 64 + ch]);
        bfr[f] = *reinterpret_cast<const s8v*>(&Bsm[cur][(wc * 64 + f * 16 + l15) * 64 + ch]);
      }
#pragma unroll
      for (int fr = 0; fr < 4; fr++)
#pragma unroll
        for (int fc = 0; fc < 4; fc++)
          acc[fr][fc] = __builtin_amdgcn_mfma_f32_16x16x32_bf16(af[fr], bfr[fc], acc[fr][fc], 0, 0, 0);
    }
    __builtin_amdgcn_s_setprio(0);
    __builtin_amdgcn_s_barrier();
  }

  // fused epilogue: cols [nb,nb+128) all in one part (1024 % 128 == 0)
  const int pnum = nb >> 10;
#pragma unroll
  for (int fr = 0; fr < 4; fr++){
    int row  = mb + wr * 64 + fr * 16 + l4 * 4;
    int b    = row >> 11;
    int nseq = row & 2047;                 // 4-aligned; +r stays in same 32/8 groups
#pragma unroll
    for (int fc = 0; fc < 4; fc++){
      int col = nb + wc * 64 + fc * 16 + l15;
      int rem = col & 1023;
      int h = rem >> 6, d = rem & 63;
      int bh = b * 16 + h;
      if (pnum == 0){          // Q (scale pre-folded into W)
        size_t base = ((size_t)bh * SEQ + nseq) * 64 + d;
#pragma unroll
        for (int r = 0; r < 4; r++)
          Qh[base + (size_t)r * 64] = f2bf(acc[fr][fc][r]);
      } else if (pnum == 1){   // K -> fragment layout (kv = nseq + r)
        int kvt = nseq >> 5, l31p = nseq & 31;       // l31p+3 <= 31
        int s = d >> 4, hh2 = (d >> 3) & 1, j = d & 7;
        size_t kbase = (((size_t)bh * 64 + kvt) * 4 + s) * 512
                     + (size_t)(hh2 * 32 + l31p) * 8 + j;
#pragma unroll
        for (int r = 0; r < 4; r++)
          Kf[kbase + (size_t)r * 8] = f2bf(acc[fr][fc][r]);
      } else {                 // V -> fragment layout (kv = nseq + r, j = (nseq&7)+r)
        int kvt = nseq >> 5, st = (nseq >> 4) & 1, hh2 = (nseq >> 3) & 1, j0 = nseq & 7;
        int dh = d >> 5, l31p = d & 31;
        size_t vbase = (((size_t)bh * 64 + kvt) * 4 + st * 2 + dh) * 512
                     + (size_t)(hh2 * 32 + l31p) * 8 + j0;
        *reinterpret_cast<ushort4*>(&Vf[vbase]) =
            make_ushort4(f2bf(acc[fr][fc][0]), f2bf(acc[fr][fc][1]),
                         f2bf(acc[fr][fc][2]), f2bf(acc[fr][fc][3]));
      }
    }
  }
}

// ---------------- out-projection GEMM (plain bf16, dbuf + swizzle) ----------------
__global__ __launch_bounds__(256, 2) void k_gemm_out(
    const ushort_t* __restrict__ Ah, const ushort_t* __restrict__ Bth,
    float* __restrict__ C, const float* __restrict__ bias){
  __shared__ __align__(16) ushort_t Asm[2][GBM * GBK];
  __shared__ __align__(16) ushort_t Bsm[2][GBM * GBK];
  const int tid  = threadIdx.x;
  const int wave = tid >> 6, lane = tid & 63;
  const int mb = blockIdx.y * GBM, nb = blockIdx.x * GBN;
  const int wr = wave >> 1, wc = wave & 1;
  const int l15 = lane & 15, l4 = lane >> 4;
  const int rsub = lane >> 3;
  const int schunk = ((lane & 7) ^ rsub) * 8;
  f32x4 acc[4][4] = {};

  auto stage = [&](int buf, int kb){
    int k0 = kb * GBK;
#pragma unroll
    for (int i = 0; i < 4; i++){
      int row = (i * 4 + wave) * 8 + rsub;
      g2l16(Ah  + (size_t)(mb + row) * 1024 + k0 + schunk, &Asm[buf][(i * 4 + wave) * 512]);
      g2l16(Bth + (size_t)(nb + row) * 1024 + k0 + schunk, &Bsm[buf][(i * 4 + wave) * 512]);
    }
  };

  stage(0, 0);

  for (int kb = 0; kb < 16; kb++){
    const int cur = kb & 1;
    if (kb < 15){
      stage(cur ^ 1, kb + 1);
      asm volatile("s_waitcnt vmcnt(8)" ::: "memory");
    } else {
      asm volatile("s_waitcnt vmcnt(0)" ::: "memory");
    }
    __builtin_amdgcn_s_barrier();
    __builtin_amdgcn_s_setprio(1);
#pragma unroll
    for (int ks = 0; ks < 2; ks++){
      s8v af[4], bfr[4];
#pragma unroll
      for (int f = 0; f < 4; f++){
        int ch = (((ks * 4 + l4) ^ (l15 & 7)) << 3);
        af[f]  = *reinterpret_cast<const s8v*>(&Asm[cur][(wr * 64 + f * 16 + l15) * 64 + ch]);
        bfr[f] = *reinterpret_cast<const s8v*>(&Bsm[cur][(wc * 64 + f * 16 + l15) * 64 + ch]);
      }
#pragma unroll
      for (int fr = 0; fr < 4; fr++)
#pragma unroll
        for (int fc = 0; fc < 4; fc++)
          acc[fr][fc] = __builtin_amdgcn_mfma_f32_16x16x32_bf16(af[fr], bfr[fc], acc[fr][fc], 0, 0, 0);
    }
    __builtin_amdgcn_s_setprio(0);
    __builtin_amdgcn_s_barrier();
  }
#pragma unroll
  for (int fr = 0; fr < 4; fr++){
    int row = mb + wr * 64 + fr * 16 + l4 * 4;
#pragma unroll
    for (int fc = 0; fc < 4; fc++){
      int col = nb + wc * 64 + fc * 16 + l15;
      float bv = bias[col];
#pragma unroll
      for (int r = 0; r < 4; r++)
        C[(size_t)(row + r) * 1024 + col] = acc[fr][fc][r] + bv;
    }
  }
}

// ---------------- flash attention (LDS-FREE: pre-fragmented K/V streams) ----------------
// Grid 512 x 256 (4 waves x 32 q-rows = 128 q/block). NO LDS, NO barriers, NO
// waitcnt asm: K/V are stored in exact MFMA-fragment order, so each wave streams
// them with perfectly-coalesced global_load_dwordx4 (1KB/instr) straight into
// MFMA operands. Working set 2MB/XCD -> L2-resident; 4 waves/block read identical
// addresses -> L1 broadcast. Register ping-pong (tiles t, t+1) lets the compiler
// software-pipeline loads across iterations. Math identical to r12/r13 (verified):
// 32x32 swapped QK -> C[kv][q]; in-register P via cvt_pk + v_permlane32_swap.
__global__ __launch_bounds__(256) void k_flash(
    const ushort_t* __restrict__ Qh, const ushort_t* __restrict__ Kf,
    const ushort_t* __restrict__ Vf, ushort_t* __restrict__ Ah){
  const int lid = blockIdx.x;             // 0..511
  const int xcd = lid & 7, g = lid >> 3;  // 8 XCDs x 64 blocks
  const int bh = xcd * 4 + (g & 3);       // each XCD owns 4 heads (K/V L2-resident)
  const int qb = (g >> 2) * 128;
  const int tid = threadIdx.x, wave = tid >> 6, lane = tid & 63;
  const int l31 = lane & 31, hh = lane >> 5;
  const int b = bh >> 4, hd = bh & 15;
  const size_t hbase = (size_t)bh * SEQ * 64;

  // Q as B-operand frags: lane(q=l31, hh) holds Q[q][d = 16s + 8hh + 0..7]
  s8v qf[4];
#pragma unroll
  for (int s = 0; s < 4; s++)
    qf[s] = *reinterpret_cast<const s8v*>(
        &Qh[hbase + (size_t)(qb + wave * 32 + l31) * 64 + s * 16 + hh * 8]);

  // per-lane fragment stream base (tile stride = 2048 ushorts)
  const ushort_t* kp = Kf + (size_t)bh * 64 * 2048 + lane * 8;
  const ushort_t* vp = Vf + (size_t)bh * 64 * 2048 + lane * 8;

  f32x16 o0 = {}, o1 = {};
  float lsum = 0.f;

  s8v kA[4], vA[4], kB[4], vB[4];

  auto loadT = [&](s8v* k, s8v* v, int t){
    const ushort_t* kt = kp + (size_t)t * 2048;
    const ushort_t* vt = vp + (size_t)t * 2048;
#pragma unroll
    for (int s = 0; s < 4; s++) k[s] = *reinterpret_cast<const s8v*>(kt + s * 512);
#pragma unroll
    for (int f = 0; f < 4; f++) v[f] = *reinterpret_cast<const s8v*>(vt + f * 512);
  };

  auto compute = [&](const s8v* k, const s8v* v){
    // QK: C[kv 0..31][q], K-dim = 64 d in 4 chained steps
    f32x16 s0 = {};
#pragma unroll
    for (int s = 0; s < 4; s++)
      s0 = __builtin_amdgcn_mfma_f32_32x32x16_bf16(k[s], qf[s], s0, 0, 0, 0);
    // fixed-max softmax + pack
    uint32 w[8];
#pragma unroll
    for (int t = 0; t < 8; t++){
      float pa = __builtin_amdgcn_exp2f(s0[2 * t]     - MFIX);
      float pb = __builtin_amdgcn_exp2f(s0[2 * t + 1] - MFIX);
      lsum += pa + pb;
      w[t] = cvt_pk_bf16(pa, pb);
    }
    // PV: P frags via permlane swaps; v[step*2 + dhalf]
#pragma unroll
    for (int st = 0; st < 2; st++){
      const int u = 4 * st;
      uint32 m0 = w[u],     m2 = w[u + 2];
      uint32 m1 = w[u + 1], m3 = w[u + 3];
      asm("v_permlane32_swap_b32 %0, %1" : "+v"(m0), "+v"(m2));
      asm("v_permlane32_swap_b32 %0, %1" : "+v"(m1), "+v"(m3));
      union { uint32 u4[4]; s8v v8; } pf;
      pf.u4[0] = m0; pf.u4[1] = m1; pf.u4[2] = m2; pf.u4[3] = m3;
      o0 = __builtin_amdgcn_mfma_f32_32x32x16_bf16(pf.v8, v[st * 2 + 0], o0, 0, 0, 0);
      o1 = __builtin_amdgcn_mfma_f32_32x32x16_bf16(pf.v8, v[st * 2 + 1], o1, 0, 0, 0);
    }
  };

  loadT(kA, vA, 0);
  loadT(kB, vB, 1);

  for (int t = 0; t < 64; t += 2){
    compute(kA, vA);
    if (t + 2 < 64) loadT(kA, vA, t + 2);
    compute(kB, vB);
    if (t + 3 < 64) loadT(kB, vB, t + 3);
  }

  // epilogue: lane holds lsum-half for q=l31; combine halves, per-reg shfl
  lsum += __shfl_xor(lsum, 32);
  float linv = 1.f / lsum;
#pragma unroll
  for (int r = 0; r < 16; r++){
    int q = (r & 3) + 8 * (r >> 2) + 4 * hh;
    float sc = __shfl(linv, q);
    int n = qb + wave * 32 + q;
    size_t rowb = (size_t)(b * SEQ + n) * 1024 + hd * 64;
    Ah[rowb + l31]      = f2bf(o0[r] * sc);
    Ah[rowb + 32 + l31] = f2bf(o1[r] * sc);
  }
}

// ---------------- host launch ----------------
extern "C" void kernel_launch(void* const* d_in, const int* in_sizes, int n_in,
                              void* d_out, int out_size, void* d_ws, size_t ws_size,
                              hipStream_t stream){
  const float* x     = (const float*)d_in[0];
  const float* w_qkv = (const float*)d_in[1];
  const float* w_out = (const float*)d_in[2];
  const float* b_out = (const float*)d_in[3];
  float* out = (float*)d_out;
  char* ws = (char*)d_ws;

  ushort_t* Xh    = (ushort_t*)(ws);                      //  8 MB
  ushort_t* Wqt_h = (ushort_t*)(ws + 8388608);            //  6 MB
  ushort_t* Wot_h = (ushort_t*)(ws + 14680064);           //  2 MB
  ushort_t* Qh    = (ushort_t*)(ws + 16777216);           //  8 MB
  ushort_t* Kf    = (ushort_t*)(ws + 25165824);           //  8 MB (fragmented)
  ushort_t* Vf    = (ushort_t*)(ws + 33554432);           //  8 MB (fragmented)
  ushort_t* Ah    = (ushort_t*)(ws + 41943040);           //  8 MB

  // 1. fused prep: x -> Xh; w_qkv -> Wqt_h (T, Q cols pre-scaled); w_out -> Wot_h (T)
  k_prep<<<5120, 256, 0, stream>>>(x, w_qkv, w_out, Xh, Wqt_h, Wot_h);
  // 2. QKV projection with fused per-head epilogue (K/V pre-fragmented)
  k_gemm_qkv<<<dim3(24, 32), 256, 0, stream>>>(Xh, Wqt_h, Qh, Kf, Vf);
  // 3. attention -> Ah (bf16), LDS-free streaming
  k_flash<<<512, 256, 0, stream>>>(Qh, Kf, Vf, Ah);
  // 4. out = Ah @ Wot + b_out
  k_gemm_out<<<dim3(8, 32), 256, 0, stream>>>(Ah, Wot_h, out, b_out);
}